// Round 3
// baseline (416.590 us; speedup 1.0000x reference)
//
#include <hip/hip_runtime.h>
#include <hip/hip_bf16.h>

#define N_NEURON 1024
#define N_PEPTIDE 16
#define N_GENES 1
#define BATCH 2048
#define SQ 32
#define DT_STEP (1.0f/120.0f)
#define S_STRIDE (N_NEURON + N_GENES + N_NEURON + N_NEURON*N_PEPTIDE) // 18433
#define LN2 0.6931471805599453f

typedef __attribute__((ext_vector_type(8))) short short8;
typedef __attribute__((ext_vector_type(4))) float floatx4;

// -------------------------------------------------------------------------
// Kernel 1: synapse (K x N fp32) -> synT (N x K bf16). LDS 32x33 transpose.
// -------------------------------------------------------------------------
__global__ __launch_bounds__(256) void synT_cast(const float* __restrict__ syn,
                                                 __hip_bfloat16* __restrict__ synT) {
    __shared__ float tile[32][33];
    const int n0 = blockIdx.x * 32;
    const int k0 = blockIdx.y * 32;
    const int tx = threadIdx.x & 31;
    const int ty = threadIdx.x >> 5;
    #pragma unroll
    for (int i = 0; i < 4; ++i)
        tile[ty + i*8][tx] = syn[(long)(k0 + ty + i*8) * N_NEURON + n0 + tx];
    __syncthreads();
    #pragma unroll
    for (int i = 0; i < 4; ++i)
        synT[(long)(n0 + ty + i*8) * N_NEURON + k0 + tx] =
            __float2bfloat16(tile[tx][ty + i*8]);
}

// -------------------------------------------------------------------------
// Kernel 2: firing + ablate/pc2 copy + partial d_neuron stage.
// -------------------------------------------------------------------------
__global__ __launch_bounds__(256) void firing_stage(
    const float* __restrict__ u,
    const float* __restrict__ state,
    const float* __restrict__ noise,
    const float* __restrict__ ndecay_g,
    const float* __restrict__ inL,
    float* __restrict__ firing_out,
    float* __restrict__ state_new,
    __hip_bfloat16* __restrict__ fbf)
{
    const int idx = blockIdx.x * 256 + threadIdx.x;
    const int b = idx >> 10, n = idx & 1023;
    const long bS = (long)b * S_STRIDE;
    const float ab = state[bS + n];
    const float nr = state[bS + N_NEURON + N_GENES + n];
    const float nm = nr * ab;
    const float ndecay = fabsf(ndecay_g[0]);
    float f = fmaxf(nr, 0.f) * ab;
    // log1p(-x) == ln(1-x): exact subtraction for x>=0.5 (Sterbenz), err<2^-25 else
    f = -(f + 0.01f) * (LN2 * __builtin_amdgcn_logf(1.0f - noise[idx]));
    f = fminf(fmaxf(f, 0.f), 10.f);
    firing_out[idx] = f;
    fbf[idx] = __float2bfloat16(f);
    state_new[bS + n] = ab;
    state_new[bS + N_NEURON + N_GENES + n] =
        nm + DT_STEP * (inL[n] * u[b] - nm * ndecay);
    if (n == 0) state_new[bS + N_NEURON] = state[bS + N_NEURON];
}

// -------------------------------------------------------------------------
// Kernel 3: peptide update, one thread per (b,n,p) element. 131072 blocks.
// -------------------------------------------------------------------------
__global__ __launch_bounds__(256) void pep_update(
    const float* __restrict__ state,
    const float* __restrict__ firing_out,
    const float* __restrict__ D,
    const float* __restrict__ prod_g,
    const float* __restrict__ decay_g,
    const float* __restrict__ pact_g,
    float* __restrict__ state_new)
{
    // swizzle: give each XCD a contiguous span of batch rows for L2 reuse
    const int wid = (blockIdx.x & 7) * (131072 / 8) + (blockIdx.x >> 3);
    const int e = wid * 256 + threadIdx.x;          // global peptide element
    const int b = e >> 14;                          // 1024*16 per row
    const int r = e & 16383;
    const int n = r >> 4;
    const int p = threadIdx.x & 15;                 // == e & 15
    const long bS = (long)b * S_STRIDE;
    const float* __restrict__ pep = state + bS + 2 * N_NEURON + N_GENES;

    const int si = n >> 5, sj = n & 31;
    const int iup = ((((si + 31) & 31) * 32 + sj) << 4) + p;
    const int idn = ((((si +  1) & 31) * 32 + sj) << 4) + p;
    const int ilf = ((si * 32 + ((sj + 31) & 31)) << 4) + p;
    const int irt = ((si * 32 + ((sj +  1) & 31)) << 4) + p;

    const float c = pep[r];
    const float lap = pep[iup] + pep[idn] + pep[ilf] + pep[irt] - 4.f * c;
    const float f = firing_out[(b << 10) + n];      // broadcast within 16 lanes
    const float upd = c + DT_STEP * (fabsf(prod_g[p]) * f
                                   - fabsf(decay_g[p]) * c
                                   + fabsf(D[p]) * lap);
    state_new[bS + 2 * N_NEURON + N_GENES + r] = upd;

    float ps = c * pact_g[p];
    ps += __shfl_xor(ps, 1);
    ps += __shfl_xor(ps, 2);
    ps += __shfl_xor(ps, 4);
    ps += __shfl_xor(ps, 8);
    if (p == 0) {
        const float pc2 = state[bS + N_NEURON];
        float* dst = state_new + bS + N_NEURON + N_GENES + n;
        *dst = *dst + DT_STEP * ps * pc2;
    }
}

// -------------------------------------------------------------------------
// Kernel 4: C = firing_bf16 @ synapse via LDS-staged bf16 MFMA 16x16x32.
// Block 256 thr = 4 waves; tile 64x64 (wave 32x32), BK=64.
// Staging: each thread loads TWO short8 rows (fix: cover all 64 rows).
// Epilogue: neuron_new = (c0 + DT*gemm) * ablate.
// -------------------------------------------------------------------------
__global__ __launch_bounds__(256) void gemm_lds(
    const __hip_bfloat16* __restrict__ A,   // fbf [2048,1024]
    const __hip_bfloat16* __restrict__ BT,  // synT [1024,1024]
    const float* __restrict__ state,
    float* __restrict__ state_new)
{
    __shared__ short As[64][72];
    __shared__ short Bs[64][72];
    const int tid = threadIdx.x;
    const int w = tid >> 6, lid = tid & 63;
    const int q = lid >> 4, l16 = lid & 15;
    const int m0 = blockIdx.x * 64;
    const int n0 = blockIdx.y * 64;
    const int scol = (tid & 7) * 8;           // 8 threads x short8 = 64 shorts/row

    floatx4 acc[2][2] = {};
    for (int k0 = 0; k0 < 1024; k0 += 64) {
        #pragma unroll
        for (int rr = 0; rr < 2; ++rr) {
            const int row = (tid >> 3) + rr * 32;   // 0..63: full tile
            *(short8*)&As[row][scol] =
                *(const short8*)(A + (long)(m0 + row) * 1024 + k0 + scol);
            *(short8*)&Bs[row][scol] =
                *(const short8*)(BT + (long)(n0 + row) * 1024 + k0 + scol);
        }
        __syncthreads();
        #pragma unroll
        for (int ks = 0; ks < 64; ks += 32) {
            short8 a[2], bb[2];
            #pragma unroll
            for (int mi = 0; mi < 2; ++mi)
                a[mi] = *(const short8*)&As[(w & 1) * 32 + mi * 16 + l16][ks + q * 8];
            #pragma unroll
            for (int ni = 0; ni < 2; ++ni)
                bb[ni] = *(const short8*)&Bs[(w >> 1) * 32 + ni * 16 + l16][ks + q * 8];
            #pragma unroll
            for (int mi = 0; mi < 2; ++mi)
                #pragma unroll
                for (int ni = 0; ni < 2; ++ni)
                    acc[mi][ni] = __builtin_amdgcn_mfma_f32_16x16x32_bf16(
                        a[mi], bb[ni], acc[mi][ni], 0, 0, 0);
        }
        __syncthreads();
    }

    #pragma unroll
    for (int mi = 0; mi < 2; ++mi)
    #pragma unroll
    for (int ni = 0; ni < 2; ++ni)
    #pragma unroll
    for (int rr = 0; rr < 4; ++rr) {
        const int m = m0 + (w & 1) * 32 + mi * 16 + q * 4 + rr;
        const int n = n0 + (w >> 1) * 32 + ni * 16 + l16;
        const long sidx = (long)m * S_STRIDE;
        const float ab = state[sidx + n];
        const float c0 = state_new[sidx + N_NEURON + N_GENES + n];
        state_new[sidx + N_NEURON + N_GENES + n] =
            (c0 + DT_STEP * acc[mi][ni][rr]) * ab;
    }
}

extern "C" void kernel_launch(void* const* d_in, const int* in_sizes, int n_in,
                              void* d_out, int out_size, void* d_ws, size_t ws_size,
                              hipStream_t stream) {
    const float* u      = (const float*)d_in[0];
    const float* state  = (const float*)d_in[1];
    const float* noise  = (const float*)d_in[2];
    const float* D      = (const float*)d_in[3];
    const float* prod   = (const float*)d_in[4];
    const float* decay  = (const float*)d_in[5];
    const float* pact   = (const float*)d_in[6];
    const float* syn    = (const float*)d_in[7];
    const float* ndec   = (const float*)d_in[8];
    const float* inL    = (const float*)d_in[9];

    float* firing = (float*)d_out;                          // [B,N]
    float* state_new = firing + (long)BATCH * N_NEURON;     // [B,S]

    __hip_bfloat16* fbf  = (__hip_bfloat16*)d_ws;           // 4 MB
    __hip_bfloat16* synT = fbf + (long)BATCH * N_NEURON;    // 2 MB

    hipLaunchKernelGGL(synT_cast, dim3(32, 32), dim3(256), 0, stream, syn, synT);
    hipLaunchKernelGGL(firing_stage, dim3(BATCH * N_NEURON / 256), dim3(256), 0, stream,
                       u, state, noise, ndec, inL, firing, state_new, fbf);
    hipLaunchKernelGGL(pep_update, dim3(131072), dim3(256), 0, stream,
                       state, firing, D, prod, decay, pact, state_new);
    hipLaunchKernelGGL(gemm_lds, dim3(32, 16), dim3(256), 0, stream,
                       fbf, synT, state, state_new);
}